// Round 4
// baseline (122.890 us; speedup 1.0000x reference)
//
#include <hip/hip_runtime.h>

// Problem constants (from reference):
//   N_KV_HEADS=8, MAX_CONTEXT=8192, HEAD_DIM=128, N_NEW=16, dtype fp32
// Output = concat(kout, vout) flat, each (1,8,8192,128) fp32.
//
// R4: keep R0's dense 1-float4-per-instruction pattern (best so far) but
// 4 grid-stride passes per thread at 2^20-float4 (16 MiB) stride:
//   - blocks 16384 -> 4096 (less launch ramp/tail)
//   - 4 independent load->store pairs per thread (more memory-level par.)
//   - pass p's cache half is compile-time: p<2 -> K, p>=2 -> V (no select)
// R2 taught: +1 dispatch ~ +6us gap, nt hurts (L3 holds the 67MB inputs).
// R3 taught: strided-within-row access slightly worse than dense.
//
// Layout in float4 units:
//   per-cache float4 count: 8*8192*32 = 2^21 ; total out = 2^22
//   i in [0,2^22): c = i>>21, j = i&(2^21-1), h = j>>18,
//                  s = (j>>5)&8191, d4 = j&31

#define NNEW 16

typedef float f32x4 __attribute__((ext_vector_type(4)));

__global__ __launch_bounds__(256) void kv_update_kernel(
    const int* __restrict__ pos,
    const f32x4* __restrict__ knew,
    const f32x4* __restrict__ vnew,
    const f32x4* __restrict__ kcache,
    const f32x4* __restrict__ vcache,
    f32x4* __restrict__ out)
{
    const unsigned int t = blockIdx.x * 256u + threadIdx.x;   // [0, 2^20)

    // All 4 element indices + source addresses first (4 loads in flight),
    // then the 4 stores. All arrays fully unrolled -> registers (rule #20 ok).
    const f32x4* src[4];
#pragma unroll
    for (int p = 0; p < 4; ++p) {
        const unsigned int i = t + ((unsigned)p << 20);       // [0, 2^22)
        const unsigned int c = (unsigned)(p >> 1);            // compile-time!
        const unsigned int j = i & ((1u << 21) - 1u);
        const unsigned int h = j >> 18;                       // head 0..7
        const int          s = (int)((j >> 5) & 8191u);       // seq position
        const unsigned int d4 = j & 31u;

        // pos is wave-uniform -> s_loads; last match wins (numpy sequential
        // assignment semantics for duplicate indices).
        int match = -1;
#pragma unroll
        for (int n = 0; n < NNEW; ++n) {
            if (pos[n] == s) match = n;
        }

        if (match >= 0) {
            // new tensor layout: (1, 8, 16, 128) -> (h*16 + n)*32 + d4
            src[p] = (c ? vnew : knew) + ((h * NNEW + (unsigned)match) * 32u + d4);
        } else {
            src[p] = (c ? vcache : kcache) + j;
        }
    }

    f32x4 v0 = *src[0];
    f32x4 v1 = *src[1];
    f32x4 v2 = *src[2];
    f32x4 v3 = *src[3];
    out[t]               = v0;
    out[t + (1u << 20)]  = v1;
    out[t + (2u << 20)]  = v2;
    out[t + (3u << 20)]  = v3;
}

extern "C" void kernel_launch(void* const* d_in, const int* in_sizes, int n_in,
                              void* d_out, int out_size, void* d_ws, size_t ws_size,
                              hipStream_t stream) {
    // setup_inputs order: pos_ids, k, v, k_cache, v_cache
    const int*   pos    = (const int*)  d_in[0];
    const f32x4* knew   = (const f32x4*)d_in[1];
    const f32x4* vnew   = (const f32x4*)d_in[2];
    const f32x4* kcache = (const f32x4*)d_in[3];
    const f32x4* vcache = (const f32x4*)d_in[4];
    f32x4*       out    = (f32x4*)d_out;

    // 2^20 threads x 4 float4s each = 2^22 float4s; 4096 blocks of 256.
    kv_update_kernel<<<(1u << 20) / 256u, 256, 0, stream>>>(
        pos, knew, vnew, kcache, vcache, out);
}

// Round 5
// 121.617 us; speedup vs baseline: 1.0105x; 1.0105x over previous
//
#include <hip/hip_runtime.h>

// Problem constants (from reference):
//   N_KV_HEADS=8, MAX_CONTEXT=8192, HEAD_DIM=128, N_NEW=16, dtype fp32
// Output = concat(kout, vout) flat, each (1,8,8192,128) fp32.
//
// R5: R0's proven dense 1-float4-per-instruction pattern, but each thread
// handles the SAME offset j in BOTH caches: out[j] (K half) and
// out[j + 2^21] (V half). The index math and the 16-compare pos match are
// computed ONCE and reused for both halves -> half R0's per-byte overhead,
// identical (fully dense) coalescing, 8192 blocks instead of 16384, and two
// independent load->store chains per thread.
// Ledger: R0 fused-dense 118.9 | R3 strided 121.4 | R4 4-pass 122.9 |
//         R2 split+nt 128.3. Poison fill writes 256 MiB => L3 cold each iter.
//
// Layout in float4 units:
//   per-cache float4 count: 8*8192*32 = 2^21 ; total out = 2^22
//   j in [0,2^21): h = j>>18, s = (j>>5)&8191, d4 = j&31

#define NNEW 16

typedef float f32x4 __attribute__((ext_vector_type(4)));

__global__ __launch_bounds__(256) void kv_update_kernel(
    const int* __restrict__ pos,
    const f32x4* __restrict__ knew,
    const f32x4* __restrict__ vnew,
    const f32x4* __restrict__ kcache,
    const f32x4* __restrict__ vcache,
    f32x4* __restrict__ out)
{
    const unsigned int j = blockIdx.x * 256u + threadIdx.x;   // [0, 2^21)
    const unsigned int h  = j >> 18;                 // head, 0..7
    const int          s  = (int)((j >> 5) & 8191u); // seq position
    const unsigned int d4 = j & 31u;                 // float4 idx in head_dim

    // pos is wave-uniform (constant offsets off a kernarg pointer) -> s_loads.
    // Last match wins => numpy sequential-assignment semantics for dups.
    int match = -1;
#pragma unroll
    for (int n = 0; n < NNEW; ++n) {
        if (pos[n] == s) match = n;
    }

    const f32x4* __restrict__ ksrc;
    const f32x4* __restrict__ vsrc;
    if (match >= 0) {
        // new tensor layout: (1, 8, 16, 128) -> (h*16 + n)*32 + d4 float4s
        const unsigned int o = (h * NNEW + (unsigned)match) * 32u + d4;
        ksrc = knew + o;
        vsrc = vnew + o;
    } else {
        ksrc = kcache + j;
        vsrc = vcache + j;
    }

    // Two independent load->store chains (K half, V half).
    f32x4 kv = *ksrc;
    f32x4 vv = *vsrc;
    out[j]              = kv;
    out[j + (1u << 21)] = vv;
}

extern "C" void kernel_launch(void* const* d_in, const int* in_sizes, int n_in,
                              void* d_out, int out_size, void* d_ws, size_t ws_size,
                              hipStream_t stream) {
    // setup_inputs order: pos_ids, k, v, k_cache, v_cache
    const int*   pos    = (const int*)  d_in[0];
    const f32x4* knew   = (const f32x4*)d_in[1];
    const f32x4* vnew   = (const f32x4*)d_in[2];
    const f32x4* kcache = (const f32x4*)d_in[3];
    const f32x4* vcache = (const f32x4*)d_in[4];
    f32x4*       out    = (f32x4*)d_out;

    // 2^21 threads, 32 B each (K+V); 256 threads/block -> 8192 blocks.
    kv_update_kernel<<<(1u << 21) / 256u, 256, 0, stream>>>(
        pos, knew, vnew, kcache, vcache, out);
}

// Round 6
// 119.660 us; speedup vs baseline: 1.0270x; 1.0164x over previous
//
#include <hip/hip_runtime.h>

// Problem constants (from reference):
//   N_KV_HEADS=8, MAX_CONTEXT=8192, HEAD_DIM=128, N_NEW=16, dtype fp32
// Output = concat(kout, vout) flat, each (1,8,8192,128) fp32.
//
// R6: REVERT to the proven-best R0 kernel. Session ledger:
//   R0 fused-dense 1xfloat4/thread : 118.9 us   <-- best
//   R3 64B/thread strided          : 121.4 us
//   R5 K/V-paired 32B/thread       : 121.6 us
//   R4 4-pass grid-stride          : 122.9 us
//   R2 split copy(nt)+scatter      : 128.3 us
// Every structural departure lost. Timed region = 2x256MiB poison fills
// (~84us, evicts L3 -> inputs cold) + reset memsets/gaps (~5-10us) + kernel
// (~29us vs 21.5us ideal at 6.3TB/s). Remaining headroom ~4-8us; all
// mechanism-backed levers tested and falsified -> this is the floor.
//
// Layout in float4 units:
//   per-cache float4 count: 8*8192*(128/4) = 2^21 ; total output 2^22
//   j (index within one cache): h = j>>18, s = (j>>5)&8191, d4 = j&31

#define NNEW 16

__global__ __launch_bounds__(256) void kv_update_kernel(
    const int* __restrict__ pos,
    const float4* __restrict__ knew,
    const float4* __restrict__ vnew,
    const float4* __restrict__ kcache,
    const float4* __restrict__ vcache,
    float4* __restrict__ out)
{
    const unsigned int i = blockIdx.x * 256u + threadIdx.x;   // [0, 2^22)

    const unsigned int is_v = i >> 21;
    const unsigned int j = i & ((1u << 21) - 1u);
    const unsigned int h  = j >> 18;          // head, 0..7
    const int          s  = (int)((j >> 5) & 8191u);  // seq position
    const unsigned int d4 = j & 31u;          // float4 index within head_dim

    // pos is wave-uniform (constant offsets off a kernarg pointer) -> s_loads.
    // Last match wins => numpy sequential-assignment semantics for dup indices.
    int match = -1;
#pragma unroll
    for (int n = 0; n < NNEW; ++n) {
        if (pos[n] == s) match = n;
    }

    float4 val;
    if (match >= 0) {
        const float4* __restrict__ src = is_v ? vnew : knew;
        // new tensor layout: (1, 8, 16, 128) -> (h*16 + n)*32 + d4 float4s
        val = src[(h * NNEW + (unsigned)match) * 32u + d4];
    } else {
        const float4* __restrict__ src = is_v ? vcache : kcache;
        val = src[j];
    }
    out[i] = val;
}

extern "C" void kernel_launch(void* const* d_in, const int* in_sizes, int n_in,
                              void* d_out, int out_size, void* d_ws, size_t ws_size,
                              hipStream_t stream) {
    // setup_inputs order: pos_ids, k, v, k_cache, v_cache
    const int*    pos    = (const int*)   d_in[0];
    const float4* knew   = (const float4*)d_in[1];
    const float4* vnew   = (const float4*)d_in[2];
    const float4* kcache = (const float4*)d_in[3];
    const float4* vcache = (const float4*)d_in[4];
    float4*       out    = (float4*)d_out;

    // total float4 elements = 2 caches * 2^21 = 2^22 ; 256 threads/block
    const unsigned int nblocks = (1u << 22) / 256u;  // 16384
    kv_update_kernel<<<nblocks, 256, 0, stream>>>(pos, knew, vnew, kcache, vcache, out);
}